// Round 5
// baseline (613.555 us; speedup 1.0000x reference)
//
#include <hip/hip_runtime.h>
#include <cmath>

// ---------------------------------------------------------------------------
// Problem: out = x @ dequant(qweight, meta, scale)
//   x      : fp32 [M,K]  (reference fp16 realized as float32 on device!)
//   qweight: int32 [K,N] in [0,16)
//   meta   : int32 [K/4,N] in [0,6)
//   scale  : fp32 [K/128,N]  (fp16 realized as fp32)
//   out    : fp32 [M,N]
// Round 5 root-cause: rounds 1-4 bit-identical absmax 2.882e20 = 7.8125*2^65.
// fp16->fp32 upcast zero-pads mantissa; low ushort of each float in
// {0,0x2000,...,0xE000} -> read as bf16 gives +-2^65 garbage. All 16-bit
// float tensors here are actually fp32. Fix: convert x to bf16 in ws,
// fp32 scale/out. DMA GEMM structure proven correct (R1 == R4 bitwise).
// ---------------------------------------------------------------------------

typedef __attribute__((ext_vector_type(8))) short bf16x8;
typedef __attribute__((ext_vector_type(4))) float f32x4;

__device__ inline unsigned short f2bf(float f) {
    union { float f; unsigned u; } v; v.f = f;
    unsigned r = (v.u + 0x7FFFu + ((v.u >> 16) & 1u)) >> 16;  // RNE
    return (unsigned short)r;
}

// ---------------------------------------------------------------------------
// Kernel 0: x fp32 -> bf16, 8 elements/thread, fully coalesced.
// ---------------------------------------------------------------------------
__global__ __launch_bounds__(256) void convert_x(
    const float* __restrict__ x, unsigned short* __restrict__ xb, long long total)
{
    const long long base = ((long long)blockIdx.x * 256 + threadIdx.x) * 8;
    if (base + 8 > total) return;
    const float4 a = *reinterpret_cast<const float4*>(x + base);
    const float4 b = *reinterpret_cast<const float4*>(x + base + 4);
    uint4 o;
    o.x = (unsigned)f2bf(a.x) | ((unsigned)f2bf(a.y) << 16);
    o.y = (unsigned)f2bf(a.z) | ((unsigned)f2bf(a.w) << 16);
    o.z = (unsigned)f2bf(b.x) | ((unsigned)f2bf(b.y) << 16);
    o.w = (unsigned)f2bf(b.z) | ((unsigned)f2bf(b.w) << 16);
    *reinterpret_cast<uint4*>(xb + base) = o;
}

// ---------------------------------------------------------------------------
// Kernel 1: dequant + transpose one N-chunk. Tile = 64(k) x 64(n) per block.
// Pattern LUT nibbles (bit j set <=> k%4==j nonzero):
//   [1100]->3 [1010]->5 [1001]->9 [0110]->6 [0101]->A [0011]->C => 0xCA6953
// ---------------------------------------------------------------------------
__global__ __launch_bounds__(256) void dequant_wt(
    const int* __restrict__ q, const int* __restrict__ meta,
    const float* __restrict__ scale,
    unsigned short* __restrict__ wt,   // [NC, K] chunk-local, bf16
    int K, int N, int nbase)
{
    __shared__ __align__(16) unsigned short lds[64 * 68];  // [n][k], stride 68
    const int t  = threadIdx.x;
    const int n  = t & 63;
    const int kc = t >> 6;
    const int k0 = blockIdx.x * 64;
    const int nl0 = blockIdx.y * 64;
    const int ng = nbase + nl0 + n;
    const int g = k0 >> 7;        // 64-row k-tile within one 128-row group
    const float sc = scale[(size_t)g * N + ng];
    const unsigned lut = 0xCA6953u;

    #pragma unroll
    for (int p = 0; p < 4; ++p) {
        const int kl = p * 16 + kc * 4;
        const int kg = k0 + kl;
        const int mv = meta[(size_t)(kg >> 2) * N + ng];
        const unsigned pat = (lut >> (mv * 4)) & 0xFu;
        unsigned short w[4];
        #pragma unroll
        for (int j = 0; j < 4; ++j) {
            const int qv = q[(size_t)(kg + j) * N + ng];
            const float wf = ((pat >> j) & 1u) ? (float)(qv - 8) * sc : 0.0f;
            w[j] = f2bf(wf);
        }
        uint2 pk;
        pk.x = (unsigned)w[0] | ((unsigned)w[1] << 16);
        pk.y = (unsigned)w[2] | ((unsigned)w[3] << 16);
        *reinterpret_cast<uint2*>(&lds[n * 68 + kl]) = pk;
    }
    __syncthreads();
    #pragma unroll
    for (int p = 0; p < 2; ++p) {
        const int idx = p * 256 + t;
        const int nr  = idx >> 3;
        const int ch  = idx & 7;
        const uint2 lo = *reinterpret_cast<const uint2*>(&lds[nr * 68 + ch * 8]);
        const uint2 hi = *reinterpret_cast<const uint2*>(&lds[nr * 68 + ch * 8 + 4]);
        uint4 vv; vv.x = lo.x; vv.y = lo.y; vv.z = hi.x; vv.w = hi.y;
        *reinterpret_cast<uint4*>(&wt[(size_t)(nl0 + nr) * K + k0 + ch * 8]) = vv;
    }
}

// ---------------------------------------------------------------------------
// Kernel 2: C[:, nbase+..] = A[M,K] * Bt[NC,K]^T, bf16 in, fp32 out.
// 128x128 tile, BK=32, 4 waves (2x2), 4x4 mfma_f32_16x16x32_bf16 per wave.
// Staging via global_load_lds width=16; XOR chunk swizzle (slot = kc^(row&3))
// cuts frag ds_read_b128 conflicts without padding (DMA dest is wave-uniform
// base + lane*16). Functional equivalence of this path proven R1==R4 bitwise.
// ---------------------------------------------------------------------------
__global__ __launch_bounds__(256, 2) void gemm_bt(
    const unsigned short* __restrict__ A,   // bf16 [M,K] (converted x)
    const unsigned short* __restrict__ Bt,  // bf16 [NC,K] chunk-local
    float* __restrict__ C,                  // fp32 [M,N]
    int M, int N, int K, int nbase)
{
    __shared__ __align__(16) unsigned short As[128 * 32];
    __shared__ __align__(16) unsigned short Bs[128 * 32];

    const int t    = threadIdx.x;
    const int wave = t >> 6;
    const int lane = t & 63;
    const int quad = lane >> 4;
    const int l16  = lane & 15;

    const int n0 = blockIdx.x * 128;  // chunk-local n tile base
    const int m0 = blockIdx.y * 128;
    const int wm = (wave & 1) * 64;
    const int wn = (wave >> 1) * 64;

    // staging: chunk ci -> row = ci>>2, slot = ci&3, global kchunk = slot^(row&3)
    const int ci0 = wave * 64 + lane;
    const int ci1 = 256 + ci0;
    const int r0 = ci0 >> 2, kc0 = (ci0 & 3) ^ (r0 & 3);
    const int r1 = ci1 >> 2, kc1 = (ci1 & 3) ^ (r1 & 3);

    const unsigned short* aG0 = A  + (size_t)(m0 + r0) * K + kc0 * 8;
    const unsigned short* aG1 = A  + (size_t)(m0 + r1) * K + kc1 * 8;
    const unsigned short* bG0 = Bt + (size_t)(n0 + r0) * K + kc0 * 8;
    const unsigned short* bG1 = Bt + (size_t)(n0 + r1) * K + kc1 * 8;

    unsigned short* aL0 = As + wave * 512;          // wave-uniform LDS bases
    unsigned short* aL1 = As + 2048 + wave * 512;
    unsigned short* bL0 = Bs + wave * 512;
    unsigned short* bL1 = Bs + 2048 + wave * 512;

    f32x4 acc[4][4];
    #pragma unroll
    for (int i = 0; i < 4; ++i)
        #pragma unroll
        for (int j = 0; j < 4; ++j)
            acc[i][j] = (f32x4){0.f, 0.f, 0.f, 0.f};

    const int sw   = (quad ^ (l16 & 3)) * 8;  // frag k-chunk slot after swizzle
    const int arow = wm + l16;
    const int brow = wn + l16;

    for (int kb = 0; kb < K; kb += 32) {
        __builtin_amdgcn_global_load_lds(
            (const __attribute__((address_space(1))) void*)aG0,
            (__attribute__((address_space(3))) void*)aL0, 16, 0, 0);
        __builtin_amdgcn_global_load_lds(
            (const __attribute__((address_space(1))) void*)aG1,
            (__attribute__((address_space(3))) void*)aL1, 16, 0, 0);
        __builtin_amdgcn_global_load_lds(
            (const __attribute__((address_space(1))) void*)bG0,
            (__attribute__((address_space(3))) void*)bL0, 16, 0, 0);
        __builtin_amdgcn_global_load_lds(
            (const __attribute__((address_space(1))) void*)bG1,
            (__attribute__((address_space(3))) void*)bL1, 16, 0, 0);
        __builtin_amdgcn_s_waitcnt(0);   // vmcnt(0): LDS DMA landed
        __syncthreads();

        bf16x8 af[4], bfr[4];
        #pragma unroll
        for (int i = 0; i < 4; ++i)
            af[i] = *reinterpret_cast<const bf16x8*>(&As[(arow + i * 16) * 32 + sw]);
        #pragma unroll
        for (int j = 0; j < 4; ++j)
            bfr[j] = *reinterpret_cast<const bf16x8*>(&Bs[(brow + j * 16) * 32 + sw]);

        #pragma unroll
        for (int i = 0; i < 4; ++i)
            #pragma unroll
            for (int j = 0; j < 4; ++j)
                acc[i][j] = __builtin_amdgcn_mfma_f32_16x16x32_bf16(
                    af[i], bfr[j], acc[i][j], 0, 0, 0);

        __syncthreads();
        aG0 += 32; aG1 += 32; bG0 += 32; bG1 += 32;
    }

    // epilogue: C/D layout col = lane&15, row = quad*4 + reg  (m89-verified)
    #pragma unroll
    for (int i = 0; i < 4; ++i) {
        const int mrow = m0 + wm + i * 16 + quad * 4;
        #pragma unroll
        for (int j = 0; j < 4; ++j) {
            const int ncol = nbase + n0 + wn + j * 16 + l16;  // global n
            #pragma unroll
            for (int r = 0; r < 4; ++r)
                C[(size_t)(mrow + r) * N + ncol] = acc[i][j][r];
        }
    }
}

extern "C" void kernel_launch(void* const* d_in, const int* in_sizes, int n_in,
                              void* d_out, int out_size, void* d_ws, size_t ws_size,
                              hipStream_t stream)
{
    const float* x     = (const float*)d_in[0];   // fp32 [M,K]
    const int*   q     = (const int*)d_in[1];     // [K,N]
    const int*   meta  = (const int*)d_in[2];     // [K/4,N]
    const float* scale = (const float*)d_in[3];   // fp32 [K/128,N]
    float*       out   = (float*)d_out;           // fp32 [M,N]

    // M*K = s0, K*N = s1, M*N = out_size  =>  K = sqrt(s0*s1/out)
    const double s0 = (double)in_sizes[0];
    const double s1 = (double)in_sizes[1];
    const int K = (int)llround(sqrt(s0 * s1 / (double)out_size));
    const int M = in_sizes[0] / K;
    const int N = in_sizes[1] / K;

    // ws layout: [ x_bf16 : M*K*2 bytes ][ wt chunk : NC*K*2 bytes ]
    unsigned short* xb = (unsigned short*)d_ws;
    const size_t xb_bytes = (size_t)M * (size_t)K * 2;
    unsigned short* wt = (unsigned short*)((char*)d_ws + xb_bytes);
    const size_t wt_avail = ws_size > xb_bytes ? ws_size - xb_bytes : 0;

    const long long total = (long long)M * K;
    convert_x<<<dim3((unsigned)((total / 8 + 255) / 256)), dim3(256), 0, stream>>>(
        x, xb, total);

    long long maxrows = (long long)(wt_avail / ((size_t)K * 2));
    int NC = (int)((maxrows / 128) * 128);
    if (NC > N) NC = N;
    if (NC < 128) NC = 128;  // requires ws_size >= xb + 1 MiB

    for (int nbase = 0; nbase < N; nbase += NC) {
        const int nc = (N - nbase) < NC ? (N - nbase) : NC;
        dim3 g1(K / 64, nc / 64);
        dequant_wt<<<g1, dim3(256), 0, stream>>>(q, meta, scale, wt, K, N, nbase);
        dim3 g2(nc / 128, M / 128);
        gemm_bt<<<g2, dim3(256), 0, stream>>>(xb, wt, out, M, N, K, nbase);
    }
}